// Round 12
// baseline (461.946 us; speedup 1.0000x reference)
//

#include <hip/hip_runtime.h>
#include <hip/hip_bf16.h>

// Deterministic hard_voxelize. Round 12: the insert kernel itself emits the
// ~49K duplicate points (CAS-loser appends self; atomicMin-winner appends the
// displaced old min — each non-first point identified exactly once). This
// kills the 2M-point gather pass, pslot, and vid[] entirely. Row 0 of each
// kept voxel = its min-index point, written by k_assign. k_extras bins the
// few duplicates; k_write sort-repairs the ~4K multi-point voxels.
// Flags/scan are u8 in-place (2MB footprint, L2-resident).
// Measured law: insert = 1 random 64B-line RMW/point ~= 122us (floor).

#define MAXV 150000
#define MAXP 10
#define LCAP 16
#define GXC 1504
#define GYC 1504
#define GZC 40
#define ECAP (1 << 20)

#define OUT_COORS 7500000
#define OUT_NPV   7950000
#define OUT_VNUM  8100000

typedef unsigned char u8;
typedef unsigned short u16;
typedef unsigned int u32;
typedef unsigned long long u64;
#define EMPTY64 0xFFFFFFFFFFFFFFFFULL

__device__ __forceinline__ u16 f2bf(float v) {  // round-to-nearest-even
    u32 b = __float_as_uint(v);
    return (u16)((b + 0x7FFFu + ((b >> 16) & 1u)) >> 16);
}
__device__ __forceinline__ float bf2f(u16 u) {
    return __uint_as_float(((u32)u) << 16);
}
__device__ __forceinline__ float bfround(float v) { return bf2f(f2bf(v)); }

// Init (+ fused dtype detect in block 0): voxels=0 (coalesced, so assign/write
// only touch filled rows later), coors=-1, tab=EMPTY, pflags=0, cnt=0,
// ecount/total=0, vnum placeholder.
__global__ void k_init(float* out, u64* tab, u32* pflags32, int* cnt,
                       int hcap, int N, const u16* raw, int* dflag,
                       u32* ecount, int* total) {
    if (blockIdx.x == 0) {
        __shared__ int v32;
        __shared__ int v16;
        if (threadIdx.x == 0) { v32 = 0; v16 = 0; }
        __syncthreads();
        int r = (int)threadIdx.x * 37;
        if (r >= N) r = N > 0 ? N - 1 : 0;
        const float* p32 = (const float*)raw;
        float a3 = p32[r * 5 + 3];
        float a4 = p32[r * 5 + 4];
        float b3 = bf2f(raw[r * 5 + 3]);
        float b4 = bf2f(raw[r * 5 + 4]);
        int ok32 = (a3 == a3) && (a4 == a4) &&
                   (a3 >= -0.001f) && (a3 <= 1.001f) && (a4 >= -0.001f) && (a4 <= 1.001f);
        int okbf = (b3 == b3) && (b4 == b4) &&
                   (b3 >= -0.001f) && (b3 <= 1.001f) && (b4 >= -0.001f) && (b4 <= 1.001f);
        if (ok32) atomicAdd(&v32, 1);
        if (okbf) atomicAdd(&v16, 1);
        __syncthreads();
        if (threadIdx.x == 0) *dflag = (v16 > v32) ? 1 : 0;
    }
    int nw = (N + 3) >> 2;  // u32 words covering pflags
    int stride = gridDim.x * blockDim.x;
    for (int i = blockIdx.x * blockDim.x + threadIdx.x; i < 7500000; i += stride) {
        out[i] = 0.0f;                              // voxels region
        if (i < hcap) tab[i] = EMPTY64;
        if (i < 450000) out[OUT_COORS + i] = -1.0f;
        if (i < nw) pflags32[i] = 0u;
        if (i < MAXV) cnt[i] = 0;
        if (i == 0) { *ecount = 0u; *total = 0; out[OUT_VNUM] = 149504.0f; }
    }
}

__device__ __forceinline__ float load_ch(const void* pts, int i, int j, int bf) {
    if (bf) return bf2f(((const u16*)pts)[i * 5 + j]);
    return ((const float*)pts)[i * 5 + j];
}

// Exact f32 sub+div+floor, matching reference arithmetic. -1 if out of range.
__device__ __forceinline__ int point_key(const void* pts, int i, int bf) {
    float x = load_ch(pts, i, 0, bf);
    float y = load_ch(pts, i, 1, bf);
    float z = load_ch(pts, i, 2, bf);
    int cx = (int)floorf((x - (-75.2f)) / 0.1f);
    int cy = (int)floorf((y - (-75.2f)) / 0.1f);
    int cz = (int)floorf((z - (-2.0f)) / 0.15f);
    if (cx < 0 || cx >= GXC || cy < 0 || cy >= GYC || cz < 0 || cz >= GZC) return -1;
    return (cz * GYC + cy) * GXC + cx;
}

// Canonical kernel: packed insert (key<<32|min_idx) + duplicate emission.
// Every non-first point appended exactly once: CAS-loser appends itself;
// a successful atomicMin appends the displaced previous min.
__global__ void Voxelization_87136296501765_kernel(
        const void* pts, int N, const int* dflag,
        u64* tab, unsigned hmask, u64* extras, u32* ecount) {
    int i = blockIdx.x * blockDim.x + threadIdx.x;
    bool has_extra = false;
    u32 eslot = 0, eidx = 0;
    if (i < N) {
        int key = point_key(pts, i, *dflag);
        if (key >= 0) {
            u64 mine = ((u64)(u32)key << 32) | (u32)i;
            unsigned slot = ((unsigned)key * 2654435761u) & hmask;
            for (;;) {
                u64 prev = atomicCAS(&tab[slot], EMPTY64, mine);
                if (prev == EMPTY64) break;           // first writer, no extra
                if ((u32)(prev >> 32) == (u32)key) {  // same voxel -> duplicate
                    u32 pm = (u32)prev;
                    if (pm > (u32)i) {
                        u64 old = atomicMin(&tab[slot], mine);
                        u32 om = (u32)old;
                        eidx = (om > (u32)i) ? om : (u32)i;  // displaced or self
                    } else {
                        eidx = (u32)i;                       // self is extra
                    }
                    eslot = slot;
                    has_extra = true;
                    break;
                }
                slot = (slot + 1) & hmask;
            }
        }
    }
    // wave-aggregated append (1 atomic per wave that has any extras)
    unsigned long long m = __ballot(has_extra);
    if (m) {
        int lane = (int)(threadIdx.x & 63);
        int leader = (int)__ffsll((unsigned long long)m) - 1;
        unsigned base = 0;
        if (lane == leader) base = atomicAdd(ecount, (unsigned)__popcll(m));
        base = (unsigned)__shfl((int)base, leader, 64);
        if (has_extra) {
            unsigned r = (unsigned)__popcll(m & ((1ull << lane) - 1ull));
            unsigned pos = base + r;
            if (pos < ECAP) extras[pos] = ((u64)eslot << 32) | eidx;
        }
    }
}

// Mark first-occurrence point indices (u8 scatter into 2MB, L2-resident).
__global__ void k_flags(const u64* tab, int hcap, u8* pflags) {
    int s = blockIdx.x * blockDim.x + threadIdx.x;
    if (s >= hcap) return;
    u64 e = tab[s];
    if (e != EMPTY64) pflags[(u32)e] = 1;
}

// In-place u8 exclusive prefix within each 256-block (max 255 fits u8).
__global__ void k_scan1(u8* pflags, int* bsums, int n) {
    __shared__ int sh[256];
    int t = threadIdx.x;
    int i = blockIdx.x * 256 + t;
    int v = (i < n) ? (int)pflags[i] : 0;
    sh[t] = v;
    __syncthreads();
    for (int off = 1; off < 256; off <<= 1) {
        int xv = (t >= off) ? sh[t - off] : 0;
        __syncthreads();
        sh[t] += xv;
        __syncthreads();
    }
    if (i < n) pflags[i] = (u8)(sh[t] - v);
    if (t == 255) bsums[blockIdx.x] = sh[255];
}

// Chunk-serial single-block scan of bsums -> bpre; also writes total + vnum.
__global__ void k_scan2(const int* bsums, int* bpre, int nb, int* total, float* out) {
    __shared__ int sh[256];
    int t = threadIdx.x;
    int C = (nb + 255) / 256;
    int lo = t * C;
    int hi = lo + C < nb ? lo + C : nb;
    int s = 0;
    for (int i = lo; i < hi; i++) s += bsums[i];
    sh[t] = s;
    __syncthreads();
    for (int off = 1; off < 256; off <<= 1) {
        int xv = (t >= off) ? sh[t - off] : 0;
        __syncthreads();
        sh[t] += xv;
        __syncthreads();
    }
    int run = sh[t] - s;
    for (int i = lo; i < hi; i++) { bpre[i] = run; run += bsums[i]; }
    if (t == 255) {
        int T = sh[255];
        *total = T;
        if (T > MAXV) T = MAXV;
        out[OUT_VNUM] = bfround((float)T);
    }
}

// Per occupied slot: vid = rank of first index; write coors + voxel row 0
// (the first point's channels). tab left intact (extras need key|first).
__global__ void k_assign(const u64* tab, int hcap, const u8* pflags,
                         const int* bpre, const void* pts, const int* dflag,
                         float* out) {
    int s = blockIdx.x * blockDim.x + threadIdx.x;
    if (s >= hcap) return;
    u64 e = tab[s];
    if (e == EMPTY64) return;
    u32 f = (u32)e;
    int v = (int)pflags[f] + bpre[f >> 8];
    if (v >= MAXV) return;
    u32 key = (u32)(e >> 32);
    int cx = (int)(key % GXC);
    u32 r = key / GXC;
    int cy = (int)(r % GYC);
    int cz = (int)(r / GYC);
    out[OUT_COORS + v * 3 + 0] = bfround((float)cz);
    out[OUT_COORS + v * 3 + 1] = bfround((float)cy);
    out[OUT_COORS + v * 3 + 2] = bfround((float)cx);
    int bf = *dflag;
    float* dst = out + (size_t)v * MAXP * 5;
    for (int j = 0; j < 5; j++) dst[j] = bfround(load_ch(pts, (int)f, j, bf));
}

// Bin the ~49K duplicates into cnt/lists (only those in kept voxels survive).
__global__ void k_extras(const u64* extras, const u32* ecount, const u64* tab,
                         const u8* pflags, const int* bpre,
                         int* cnt, int* lists) {
    unsigned j = blockIdx.x * blockDim.x + threadIdx.x;
    unsigned ec = *ecount;
    if (ec > ECAP) ec = ECAP;
    if (j >= ec) return;
    u64 rec = extras[j];
    u32 slot = (u32)(rec >> 32);
    u32 pidx = (u32)rec;
    u64 e = tab[slot];
    u32 f = (u32)e;
    int v = (int)pflags[f] + bpre[f >> 8];
    if (v >= MAXV) return;
    int pos = atomicAdd(&cnt[v], 1);
    if (pos < LCAP) lists[v * LCAP + pos] = (int)pidx;
}

// npv for all voxels + sorted repair rows 1..np-1 for multi-point voxels.
// Rows >= np are already zero (init); row 0 written by k_assign.
__global__ void k_write(const void* pts, const int* dflag, const int* cnt,
                        const int* lists, const int* total, float* out) {
    int v = blockIdx.x * blockDim.x + threadIdx.x;
    if (v >= MAXV) return;
    int T = *total;
    if (T > MAXV) T = MAXV;
    if (v >= T) { out[OUT_NPV + v] = 0.0f; return; }
    int c = cnt[v];
    int np = 1 + c;
    if (np > MAXP) np = MAXP;
    out[OUT_NPV + v] = (float)np;
    if (c <= 0) return;
    int m = (c < LCAP) ? c : LCAP;
    int idx[LCAP];
    for (int j = 0; j < m; j++) idx[j] = lists[v * LCAP + j];
    for (int a = 1; a < m; a++) {  // sort duplicate indices ascending
        int kk = idx[a];
        int b = a - 1;
        while (b >= 0 && idx[b] > kk) { idx[b + 1] = idx[b]; b--; }
        idx[b + 1] = kk;
    }
    int bf = *dflag;
    float* dst = out + (size_t)v * MAXP * 5;
    for (int r = 1; r < np; r++) {
        int p = idx[r - 1];
        for (int j = 0; j < 5; j++)
            dst[r * 5 + j] = bfround(load_ch(pts, p, j, bf));
    }
}

extern "C" void kernel_launch(void* const* d_in, const int* in_sizes, int n_in,
                              void* d_out, int out_size, void* d_ws, size_t ws_size,
                              hipStream_t stream) {
    (void)n_in; (void)out_size;
    const void* pts = d_in[0];
    int N = in_sizes[0] / 5;
    float* out = (float*)d_out;
    if (N <= 0 || N > 16384 * 256) return;

    // ws: tab[hcap]*8 | pflags[N pad256] | bsums[16384] bpre[16384] |
    //     total dflag ecount | cnt[MAXV] | lists[MAXV*LCAP] | extras[ECAP]*8
    size_t npad = ((size_t)N + 255) & ~(size_t)255;
    size_t fixed = npad + 16384 * 8 + 512 + (size_t)MAXV * 4
                 + (size_t)MAXV * LCAP * 4 + (size_t)ECAP * 8;
    int hcap = 0;
    if (ws_size >= fixed + (((size_t)8) << 22))      hcap = 1 << 22;  // ~54 MB
    else if (ws_size >= fixed + (((size_t)8) << 21)) hcap = 1 << 21;  // ~37 MB
    if (hcap == 0) return;
    unsigned hmask = (unsigned)(hcap - 1);

    char* w = (char*)d_ws;
    u64* tab    = (u64*)w;  w += (size_t)hcap * 8;
    u8*  pflags = (u8*)w;   w += npad;
    int* bsums  = (int*)w;  w += 16384 * 4;
    int* bpre   = (int*)w;  w += 16384 * 4;
    int* total  = (int*)w;  w += 128;
    int* dflag  = (int*)w;  w += 128;
    u32* ecount = (u32*)w;  w += 256;
    int* cnt    = (int*)w;  w += (size_t)MAXV * 4;
    int* lists  = (int*)w;  w += (size_t)MAXV * LCAP * 4;
    u64* extras = (u64*)w;

    int nb  = (N + 255) / 256;
    int nbh = (hcap + 255) / 256;

    k_init<<<4096, 256, 0, stream>>>(out, tab, (u32*)pflags, cnt, hcap, N,
                                     (const u16*)pts, dflag, ecount, total);
    Voxelization_87136296501765_kernel<<<nb, 256, 0, stream>>>(
        pts, N, dflag, tab, hmask, extras, ecount);
    k_flags<<<nbh, 256, 0, stream>>>(tab, hcap, pflags);
    k_scan1<<<nb, 256, 0, stream>>>(pflags, bsums, N);
    k_scan2<<<1, 256, 0, stream>>>(bsums, bpre, nb, total, out);
    k_assign<<<nbh, 256, 0, stream>>>(tab, hcap, pflags, bpre, pts, dflag, out);
    k_extras<<<ECAP / 256, 256, 0, stream>>>(extras, ecount, tab, pflags, bpre,
                                             cnt, lists);
    k_write<<<(MAXV + 255) / 256, 256, 0, stream>>>(pts, dflag, cnt, lists,
                                                    total, out);
}


// Round 13
// 285.081 us; speedup vs baseline: 1.6204x; 1.6204x over previous
//

#include <hip/hip_runtime.h>
#include <hip/hip_bf16.h>

// Deterministic hard_voxelize. Round 13: R12's duplicate-emission design with
// the contention bug fixed. R12's single global ecount line took ~25K
// device-scope same-line RMWs (~7ns each ~= +175us, measured). Now: per-block
// LDS counter + per-block extras segment + rare global overflow. The extras
// SET is deterministic (CAS-loser appends self; successful atomicMin appends
// the displaced old min), so downstream results are order-independent.
// Measured law: insert = 1 random 64B-line RMW/point ~= 122us (floor).

#define MAXV 150000
#define MAXP 10
#define LCAP 16
#define GXC 1504
#define GYC 1504
#define GZC 40
#define SEGC 64            // extras segment per block (expect ~6, max seen ~25)
#define OCAP (1 << 18)     // global overflow (adversarial only)

#define OUT_COORS 7500000
#define OUT_NPV   7950000
#define OUT_VNUM  8100000

typedef unsigned char u8;
typedef unsigned short u16;
typedef unsigned int u32;
typedef unsigned long long u64;
#define EMPTY64 0xFFFFFFFFFFFFFFFFULL

__device__ __forceinline__ u16 f2bf(float v) {  // round-to-nearest-even
    u32 b = __float_as_uint(v);
    return (u16)((b + 0x7FFFu + ((b >> 16) & 1u)) >> 16);
}
__device__ __forceinline__ float bf2f(u16 u) {
    return __uint_as_float(((u32)u) << 16);
}
__device__ __forceinline__ float bfround(float v) { return bf2f(f2bf(v)); }

// Init (+ fused dtype detect in block 0): voxels=0, coors=-1, tab=EMPTY,
// pflags=0, cnt=0, ocount/total=0, vnum placeholder.
__global__ void k_init(float* out, u64* tab, u32* pflags32, int* cnt,
                       int hcap, int N, const u16* raw, int* dflag,
                       u32* ocount, int* total) {
    if (blockIdx.x == 0) {
        __shared__ int v32;
        __shared__ int v16;
        if (threadIdx.x == 0) { v32 = 0; v16 = 0; }
        __syncthreads();
        int r = (int)threadIdx.x * 37;
        if (r >= N) r = N > 0 ? N - 1 : 0;
        const float* p32 = (const float*)raw;
        float a3 = p32[r * 5 + 3];
        float a4 = p32[r * 5 + 4];
        float b3 = bf2f(raw[r * 5 + 3]);
        float b4 = bf2f(raw[r * 5 + 4]);
        int ok32 = (a3 == a3) && (a4 == a4) &&
                   (a3 >= -0.001f) && (a3 <= 1.001f) && (a4 >= -0.001f) && (a4 <= 1.001f);
        int okbf = (b3 == b3) && (b4 == b4) &&
                   (b3 >= -0.001f) && (b3 <= 1.001f) && (b4 >= -0.001f) && (b4 <= 1.001f);
        if (ok32) atomicAdd(&v32, 1);
        if (okbf) atomicAdd(&v16, 1);
        __syncthreads();
        if (threadIdx.x == 0) *dflag = (v16 > v32) ? 1 : 0;
    }
    int nw = (N + 3) >> 2;  // u32 words covering pflags
    int stride = gridDim.x * blockDim.x;
    for (int i = blockIdx.x * blockDim.x + threadIdx.x; i < 7500000; i += stride) {
        out[i] = 0.0f;                              // voxels region
        if (i < hcap) tab[i] = EMPTY64;
        if (i < 450000) out[OUT_COORS + i] = -1.0f;
        if (i < nw) pflags32[i] = 0u;
        if (i < MAXV) cnt[i] = 0;
        if (i == 0) { *ocount = 0u; *total = 0; out[OUT_VNUM] = 149504.0f; }
    }
}

__device__ __forceinline__ float load_ch(const void* pts, int i, int j, int bf) {
    if (bf) return bf2f(((const u16*)pts)[i * 5 + j]);
    return ((const float*)pts)[i * 5 + j];
}

// Exact f32 sub+div+floor, matching reference arithmetic. -1 if out of range.
__device__ __forceinline__ int point_key(const void* pts, int i, int bf) {
    float x = load_ch(pts, i, 0, bf);
    float y = load_ch(pts, i, 1, bf);
    float z = load_ch(pts, i, 2, bf);
    int cx = (int)floorf((x - (-75.2f)) / 0.1f);
    int cy = (int)floorf((y - (-75.2f)) / 0.1f);
    int cz = (int)floorf((z - (-2.0f)) / 0.15f);
    if (cx < 0 || cx >= GXC || cy < 0 || cy >= GYC || cz < 0 || cz >= GZC) return -1;
    return (cz * GYC + cy) * GXC + cx;
}

// Canonical kernel: packed insert (key<<32|min_idx) + duplicate emission into
// the block's private segment (LDS counter -> zero cross-block contention).
__global__ void Voxelization_87136296501765_kernel(
        const void* pts, int N, const int* dflag,
        u64* tab, unsigned hmask, u64* extras, u32* bcount,
        u64* ovf, u32* ocount) {
    __shared__ u32 s_cnt;
    if (threadIdx.x == 0) s_cnt = 0;
    __syncthreads();
    int i = blockIdx.x * blockDim.x + threadIdx.x;
    bool has_extra = false;
    u32 eslot = 0, eidx = 0;
    if (i < N) {
        int key = point_key(pts, i, *dflag);
        if (key >= 0) {
            u64 mine = ((u64)(u32)key << 32) | (u32)i;
            unsigned slot = ((unsigned)key * 2654435761u) & hmask;
            for (;;) {
                u64 prev = atomicCAS(&tab[slot], EMPTY64, mine);
                if (prev == EMPTY64) break;           // first writer, no extra
                if ((u32)(prev >> 32) == (u32)key) {  // same voxel -> duplicate
                    u32 pm = (u32)prev;
                    if (pm > (u32)i) {
                        u64 old = atomicMin(&tab[slot], mine);
                        u32 om = (u32)old;
                        eidx = (om > (u32)i) ? om : (u32)i;  // displaced or self
                    } else {
                        eidx = (u32)i;                       // self is extra
                    }
                    eslot = slot;
                    has_extra = true;
                    break;
                }
                slot = (slot + 1) & hmask;
            }
        }
    }
    if (has_extra) {
        u32 pos = atomicAdd(&s_cnt, 1u);  // LDS atomic, block-local
        u64 rec = ((u64)eslot << 32) | eidx;
        if (pos < SEGC) {
            extras[(size_t)blockIdx.x * SEGC + pos] = rec;
        } else {
            u32 op = atomicAdd(ocount, 1u);  // adversarial-only path
            if (op < OCAP) ovf[op] = rec;
        }
    }
    __syncthreads();
    if (threadIdx.x == 0) bcount[blockIdx.x] = s_cnt;
}

// Mark first-occurrence point indices (u8 scatter, 2MB L2-resident).
__global__ void k_flags(const u64* tab, int hcap, u8* pflags) {
    int s = blockIdx.x * blockDim.x + threadIdx.x;
    if (s >= hcap) return;
    u64 e = tab[s];
    if (e != EMPTY64) pflags[(u32)e] = 1;
}

// In-place u8 exclusive prefix within each 256-block (fits u8: max 255).
__global__ void k_scan1(u8* pflags, int* bsums, int n) {
    __shared__ int sh[256];
    int t = threadIdx.x;
    int i = blockIdx.x * 256 + t;
    int v = (i < n) ? (int)pflags[i] : 0;
    sh[t] = v;
    __syncthreads();
    for (int off = 1; off < 256; off <<= 1) {
        int xv = (t >= off) ? sh[t - off] : 0;
        __syncthreads();
        sh[t] += xv;
        __syncthreads();
    }
    if (i < n) pflags[i] = (u8)(sh[t] - v);
    if (t == 255) bsums[blockIdx.x] = sh[255];
}

// Chunk-serial single-block scan of bsums -> bpre; writes total + vnum.
__global__ void k_scan2(const int* bsums, int* bpre, int nb, int* total, float* out) {
    __shared__ int sh[256];
    int t = threadIdx.x;
    int C = (nb + 255) / 256;
    int lo = t * C;
    int hi = lo + C < nb ? lo + C : nb;
    int s = 0;
    for (int i = lo; i < hi; i++) s += bsums[i];
    sh[t] = s;
    __syncthreads();
    for (int off = 1; off < 256; off <<= 1) {
        int xv = (t >= off) ? sh[t - off] : 0;
        __syncthreads();
        sh[t] += xv;
        __syncthreads();
    }
    int run = sh[t] - s;
    for (int i = lo; i < hi; i++) { bpre[i] = run; run += bsums[i]; }
    if (t == 255) {
        int T = sh[255];
        *total = T;
        if (T > MAXV) T = MAXV;
        out[OUT_VNUM] = bfround((float)T);
    }
}

// Per occupied slot: vid = rank of first index; write coors + voxel row 0.
__global__ void k_assign(const u64* tab, int hcap, const u8* pflags,
                         const int* bpre, const void* pts, const int* dflag,
                         float* out) {
    int s = blockIdx.x * blockDim.x + threadIdx.x;
    if (s >= hcap) return;
    u64 e = tab[s];
    if (e == EMPTY64) return;
    u32 f = (u32)e;
    int v = (int)pflags[f] + bpre[f >> 8];
    if (v >= MAXV) return;
    u32 key = (u32)(e >> 32);
    int cx = (int)(key % GXC);
    u32 r = key / GXC;
    int cy = (int)(r % GYC);
    int cz = (int)(r / GYC);
    out[OUT_COORS + v * 3 + 0] = bfround((float)cz);
    out[OUT_COORS + v * 3 + 1] = bfround((float)cy);
    out[OUT_COORS + v * 3 + 2] = bfround((float)cx);
    int bf = *dflag;
    float* dst = out + (size_t)v * MAXP * 5;
    for (int j = 0; j < 5; j++) dst[j] = bfround(load_ch(pts, (int)f, j, bf));
}

// Bin duplicates into cnt/lists. Blocks [0,nb): per-block segments;
// blocks [nb,..): overflow list.
__global__ void k_extras(const u64* extras, const u32* bcount, const u64* ovf,
                         const u32* ocount, int nb, const u64* tab,
                         const u8* pflags, const int* bpre,
                         int* cnt, int* lists) {
    int b = blockIdx.x;
    u64 rec;
    if (b < nb) {
        u32 c = bcount[b];
        if (c > SEGC) c = SEGC;
        if (threadIdx.x >= c) return;
        rec = extras[(size_t)b * SEGC + threadIdx.x];
    } else {
        u32 j = (u32)(b - nb) * 256 + threadIdx.x;
        u32 oc = *ocount;
        if (oc > OCAP) oc = OCAP;
        if (j >= oc) return;
        rec = ovf[j];
    }
    u32 slot = (u32)(rec >> 32);
    u32 pidx = (u32)rec;
    u64 e = tab[slot];
    u32 f = (u32)e;
    int v = (int)pflags[f] + bpre[f >> 8];
    if (v >= MAXV) return;
    int pos = atomicAdd(&cnt[v], 1);
    if (pos < LCAP) lists[v * LCAP + pos] = (int)pidx;
}

// npv for all voxels + sorted repair rows 1..np-1 for multi-point voxels.
// Rows >= np already zero (init); row 0 written by k_assign.
__global__ void k_write(const void* pts, const int* dflag, const int* cnt,
                        const int* lists, const int* total, float* out) {
    int v = blockIdx.x * blockDim.x + threadIdx.x;
    if (v >= MAXV) return;
    int T = *total;
    if (T > MAXV) T = MAXV;
    if (v >= T) { out[OUT_NPV + v] = 0.0f; return; }
    int c = cnt[v];
    int np = 1 + c;
    if (np > MAXP) np = MAXP;
    out[OUT_NPV + v] = (float)np;
    if (c <= 0) return;
    int m = (c < LCAP) ? c : LCAP;
    int idx[LCAP];
    for (int j = 0; j < m; j++) idx[j] = lists[v * LCAP + j];
    for (int a = 1; a < m; a++) {  // sort duplicate indices ascending
        int kk = idx[a];
        int b = a - 1;
        while (b >= 0 && idx[b] > kk) { idx[b + 1] = idx[b]; b--; }
        idx[b + 1] = kk;
    }
    int bf = *dflag;
    float* dst = out + (size_t)v * MAXP * 5;
    for (int r = 1; r < np; r++) {
        int p = idx[r - 1];
        for (int j = 0; j < 5; j++)
            dst[r * 5 + j] = bfround(load_ch(pts, p, j, bf));
    }
}

extern "C" void kernel_launch(void* const* d_in, const int* in_sizes, int n_in,
                              void* d_out, int out_size, void* d_ws, size_t ws_size,
                              hipStream_t stream) {
    (void)n_in; (void)out_size;
    const void* pts = d_in[0];
    int N = in_sizes[0] / 5;
    float* out = (float*)d_out;
    if (N <= 0 || N > 16384 * 256) return;

    int nb = (N + 255) / 256;

    // ws: tab[hcap]*8 | pflags[N pad256] | bsums/bpre[16384] | total dflag ocount
    //     | cnt[MAXV] | lists[MAXV*LCAP] | extras[nb*SEGC]*8 | bcount[nb] | ovf
    size_t npad = ((size_t)N + 255) & ~(size_t)255;
    size_t fixed = npad + 16384 * 8 + 512 + (size_t)MAXV * 4
                 + (size_t)MAXV * LCAP * 4 + (size_t)nb * SEGC * 8
                 + (size_t)nb * 4 + (size_t)OCAP * 8;
    int hcap = 0;
    if (ws_size >= fixed + (((size_t)8) << 22))      hcap = 1 << 22;  // ~52 MB
    else if (ws_size >= fixed + (((size_t)8) << 21)) hcap = 1 << 21;  // ~35 MB
    if (hcap == 0) return;
    unsigned hmask = (unsigned)(hcap - 1);

    char* w = (char*)d_ws;
    u64* tab    = (u64*)w;  w += (size_t)hcap * 8;
    u8*  pflags = (u8*)w;   w += npad;
    int* bsums  = (int*)w;  w += 16384 * 4;
    int* bpre   = (int*)w;  w += 16384 * 4;
    int* total  = (int*)w;  w += 128;
    int* dflag  = (int*)w;  w += 128;
    u32* ocount = (u32*)w;  w += 256;
    int* cnt    = (int*)w;  w += (size_t)MAXV * 4;
    int* lists  = (int*)w;  w += (size_t)MAXV * LCAP * 4;
    u64* extras = (u64*)w;  w += (size_t)nb * SEGC * 8;
    u32* bcount = (u32*)w;  w += (size_t)nb * 4;
    u64* ovf    = (u64*)w;

    int nbh = (hcap + 255) / 256;

    k_init<<<4096, 256, 0, stream>>>(out, tab, (u32*)pflags, cnt, hcap, N,
                                     (const u16*)pts, dflag, ocount, total);
    Voxelization_87136296501765_kernel<<<nb, 256, 0, stream>>>(
        pts, N, dflag, tab, hmask, extras, bcount, ovf, ocount);
    k_flags<<<nbh, 256, 0, stream>>>(tab, hcap, pflags);
    k_scan1<<<nb, 256, 0, stream>>>(pflags, bsums, N);
    k_scan2<<<1, 256, 0, stream>>>(bsums, bpre, nb, total, out);
    k_assign<<<nbh, 256, 0, stream>>>(tab, hcap, pflags, bpre, pts, dflag, out);
    k_extras<<<nb + OCAP / 256, 256, 0, stream>>>(extras, bcount, ovf, ocount,
                                                  nb, tab, pflags, bpre,
                                                  cnt, lists);
    k_write<<<(MAXV + 255) / 256, 256, 0, stream>>>(pts, dflag, cnt, lists,
                                                    total, out);
}


// Round 14
// 279.350 us; speedup vs baseline: 1.6536x; 1.0205x over previous
//

#include <hip/hip_runtime.h>
#include <hip/hip_bf16.h>

// Deterministic hard_voxelize. Round 14: k_flags eliminated.
// first(i) <=> valid(i) AND i not-in extras. Insert writes pflags[i]=valid
// (coalesced u8); k_clear zeroes the ~49K non-first flags from the extras
// list (49K random bytes vs R13's 33.5MB tab read + 2M random scatters).
// Measured laws: insert = 1 random 64B-line RMW/point ~= 122us (floor);
// single-hot-line device atomics ~7ns each (R12 regression).

#define MAXV 150000
#define MAXP 10
#define LCAP 16
#define GXC 1504
#define GYC 1504
#define GZC 40
#define SEGC 64            // extras segment per block (expect ~6)
#define OCAP (1 << 18)     // global overflow (adversarial only)

#define OUT_COORS 7500000
#define OUT_NPV   7950000
#define OUT_VNUM  8100000

typedef unsigned char u8;
typedef unsigned short u16;
typedef unsigned int u32;
typedef unsigned long long u64;
#define EMPTY64 0xFFFFFFFFFFFFFFFFULL

__device__ __forceinline__ u16 f2bf(float v) {  // round-to-nearest-even
    u32 b = __float_as_uint(v);
    return (u16)((b + 0x7FFFu + ((b >> 16) & 1u)) >> 16);
}
__device__ __forceinline__ float bf2f(u16 u) {
    return __uint_as_float(((u32)u) << 16);
}
__device__ __forceinline__ float bfround(float v) { return bf2f(f2bf(v)); }

// Init (+ fused dtype detect in block 0): voxels=0, coors=-1, tab=EMPTY,
// cnt=0, ocount/total=0, vnum placeholder. pflags now fully written by insert.
__global__ void k_init(float* out, u64* tab, int* cnt,
                       int hcap, int N, const u16* raw, int* dflag,
                       u32* ocount, int* total) {
    if (blockIdx.x == 0) {
        __shared__ int v32;
        __shared__ int v16;
        if (threadIdx.x == 0) { v32 = 0; v16 = 0; }
        __syncthreads();
        int r = (int)threadIdx.x * 37;
        if (r >= N) r = N > 0 ? N - 1 : 0;
        const float* p32 = (const float*)raw;
        float a3 = p32[r * 5 + 3];
        float a4 = p32[r * 5 + 4];
        float b3 = bf2f(raw[r * 5 + 3]);
        float b4 = bf2f(raw[r * 5 + 4]);
        int ok32 = (a3 == a3) && (a4 == a4) &&
                   (a3 >= -0.001f) && (a3 <= 1.001f) && (a4 >= -0.001f) && (a4 <= 1.001f);
        int okbf = (b3 == b3) && (b4 == b4) &&
                   (b3 >= -0.001f) && (b3 <= 1.001f) && (b4 >= -0.001f) && (b4 <= 1.001f);
        if (ok32) atomicAdd(&v32, 1);
        if (okbf) atomicAdd(&v16, 1);
        __syncthreads();
        if (threadIdx.x == 0) *dflag = (v16 > v32) ? 1 : 0;
    }
    int stride = gridDim.x * blockDim.x;
    for (int i = blockIdx.x * blockDim.x + threadIdx.x; i < 7500000; i += stride) {
        out[i] = 0.0f;                              // voxels region
        if (i < hcap) tab[i] = EMPTY64;
        if (i < 450000) out[OUT_COORS + i] = -1.0f;
        if (i < MAXV) cnt[i] = 0;
        if (i == 0) { *ocount = 0u; *total = 0; out[OUT_VNUM] = 149504.0f; }
    }
}

__device__ __forceinline__ float load_ch(const void* pts, int i, int j, int bf) {
    if (bf) return bf2f(((const u16*)pts)[i * 5 + j]);
    return ((const float*)pts)[i * 5 + j];
}

// Exact f32 sub+div+floor, matching reference arithmetic. -1 if out of range.
__device__ __forceinline__ int point_key(const void* pts, int i, int bf) {
    float x = load_ch(pts, i, 0, bf);
    float y = load_ch(pts, i, 1, bf);
    float z = load_ch(pts, i, 2, bf);
    int cx = (int)floorf((x - (-75.2f)) / 0.1f);
    int cy = (int)floorf((y - (-75.2f)) / 0.1f);
    int cz = (int)floorf((z - (-2.0f)) / 0.15f);
    if (cx < 0 || cx >= GXC || cy < 0 || cy >= GYC || cz < 0 || cz >= GZC) return -1;
    return (cz * GYC + cy) * GXC + cx;
}

// Canonical kernel: packed insert (key<<32|min_idx) + duplicate emission into
// the block's private segment + coalesced validity flag write.
__global__ void Voxelization_87136296501765_kernel(
        const void* pts, int N, const int* dflag,
        u64* tab, unsigned hmask, u64* extras, u32* bcount,
        u64* ovf, u32* ocount, u8* pflags) {
    __shared__ u32 s_cnt;
    if (threadIdx.x == 0) s_cnt = 0;
    __syncthreads();
    int i = blockIdx.x * blockDim.x + threadIdx.x;
    bool has_extra = false;
    u32 eslot = 0, eidx = 0;
    if (i < N) {
        int key = point_key(pts, i, *dflag);
        pflags[i] = (u8)(key >= 0);   // coalesced; firsts keep 1, k_clear zeroes dups
        if (key >= 0) {
            u64 mine = ((u64)(u32)key << 32) | (u32)i;
            unsigned slot = ((unsigned)key * 2654435761u) & hmask;
            for (;;) {
                u64 prev = atomicCAS(&tab[slot], EMPTY64, mine);
                if (prev == EMPTY64) break;           // first writer, no extra
                if ((u32)(prev >> 32) == (u32)key) {  // same voxel -> duplicate
                    u32 pm = (u32)prev;
                    if (pm > (u32)i) {
                        u64 old = atomicMin(&tab[slot], mine);
                        u32 om = (u32)old;
                        eidx = (om > (u32)i) ? om : (u32)i;  // displaced or self
                    } else {
                        eidx = (u32)i;                       // self is extra
                    }
                    eslot = slot;
                    has_extra = true;
                    break;
                }
                slot = (slot + 1) & hmask;
            }
        }
    }
    if (has_extra) {
        u32 pos = atomicAdd(&s_cnt, 1u);  // LDS atomic, block-local
        u64 rec = ((u64)eslot << 32) | eidx;
        if (pos < SEGC) {
            extras[(size_t)blockIdx.x * SEGC + pos] = rec;
        } else {
            u32 op = atomicAdd(ocount, 1u);  // adversarial-only path
            if (op < OCAP) ovf[op] = rec;
        }
    }
    __syncthreads();
    if (threadIdx.x == 0) bcount[blockIdx.x] = s_cnt;
}

// Clear non-first flags (~49K random bytes; replaces R13's k_flags).
// Blocks [0,nb): per-block segments; blocks [nb,..): overflow list.
__global__ void k_clear(const u64* extras, const u32* bcount, const u64* ovf,
                        const u32* ocount, int nb, u8* pflags) {
    int b = blockIdx.x;
    u64 rec;
    if (b < nb) {
        u32 c = bcount[b];
        if (c > SEGC) c = SEGC;
        if (threadIdx.x >= c) return;
        rec = extras[(size_t)b * SEGC + threadIdx.x];
    } else {
        u32 j = (u32)(b - nb) * 256 + threadIdx.x;
        u32 oc = *ocount;
        if (oc > OCAP) oc = OCAP;
        if (j >= oc) return;
        rec = ovf[j];
    }
    pflags[(u32)rec] = 0;  // low word = duplicate point index
}

// In-place u8 exclusive prefix within each 256-block (fits u8: max 255).
__global__ void k_scan1(u8* pflags, int* bsums, int n) {
    __shared__ int sh[256];
    int t = threadIdx.x;
    int i = blockIdx.x * 256 + t;
    int v = (i < n) ? (int)pflags[i] : 0;
    sh[t] = v;
    __syncthreads();
    for (int off = 1; off < 256; off <<= 1) {
        int xv = (t >= off) ? sh[t - off] : 0;
        __syncthreads();
        sh[t] += xv;
        __syncthreads();
    }
    if (i < n) pflags[i] = (u8)(sh[t] - v);
    if (t == 255) bsums[blockIdx.x] = sh[255];
}

// Chunk-serial single-block scan of bsums -> bpre; writes total + vnum.
__global__ void k_scan2(const int* bsums, int* bpre, int nb, int* total, float* out) {
    __shared__ int sh[256];
    int t = threadIdx.x;
    int C = (nb + 255) / 256;
    int lo = t * C;
    int hi = lo + C < nb ? lo + C : nb;
    int s = 0;
    for (int i = lo; i < hi; i++) s += bsums[i];
    sh[t] = s;
    __syncthreads();
    for (int off = 1; off < 256; off <<= 1) {
        int xv = (t >= off) ? sh[t - off] : 0;
        __syncthreads();
        sh[t] += xv;
        __syncthreads();
    }
    int run = sh[t] - s;
    for (int i = lo; i < hi; i++) { bpre[i] = run; run += bsums[i]; }
    if (t == 255) {
        int T = sh[255];
        *total = T;
        if (T > MAXV) T = MAXV;
        out[OUT_VNUM] = bfround((float)T);
    }
}

// Per occupied slot: vid = rank of first index; rewrite tab low word := vid
// (0xFFFFFFFF past cap); write coors + voxel row 0 from the first point.
__global__ void k_assign(u64* tab, int hcap, const u8* pflags,
                         const int* bpre, const void* pts, const int* dflag,
                         float* out) {
    int s = blockIdx.x * blockDim.x + threadIdx.x;
    if (s >= hcap) return;
    u64 e = tab[s];
    if (e == EMPTY64) return;
    u32 f = (u32)e;
    int v = (int)pflags[f] + bpre[f >> 8];
    u32* low = (u32*)tab + ((size_t)(unsigned)s << 1);  // LE low word
    if (v >= MAXV) { *low = 0xFFFFFFFFu; return; }
    *low = (u32)v;
    u32 key = (u32)(e >> 32);
    int cx = (int)(key % GXC);
    u32 r = key / GXC;
    int cy = (int)(r % GYC);
    int cz = (int)(r / GYC);
    out[OUT_COORS + v * 3 + 0] = bfround((float)cz);
    out[OUT_COORS + v * 3 + 1] = bfround((float)cy);
    out[OUT_COORS + v * 3 + 2] = bfround((float)cx);
    int bf = *dflag;
    float* dst = out + (size_t)v * MAXP * 5;
    for (int j = 0; j < 5; j++) dst[j] = bfround(load_ch(pts, (int)f, j, bf));
}

// Bin duplicates into cnt/lists via slot -> vid (tab low word).
__global__ void k_extras(const u64* extras, const u32* bcount, const u64* ovf,
                         const u32* ocount, int nb, const u64* tab,
                         int* cnt, int* lists) {
    int b = blockIdx.x;
    u64 rec;
    if (b < nb) {
        u32 c = bcount[b];
        if (c > SEGC) c = SEGC;
        if (threadIdx.x >= c) return;
        rec = extras[(size_t)b * SEGC + threadIdx.x];
    } else {
        u32 j = (u32)(b - nb) * 256 + threadIdx.x;
        u32 oc = *ocount;
        if (oc > OCAP) oc = OCAP;
        if (j >= oc) return;
        rec = ovf[j];
    }
    u32 slot = (u32)(rec >> 32);
    u32 pidx = (u32)rec;
    u32 v = ((const u32*)tab)[(size_t)slot << 1];  // low word = vid
    if (v >= MAXV) return;
    int pos = atomicAdd(&cnt[v], 1);
    if (pos < LCAP) lists[v * LCAP + pos] = (int)pidx;
}

// npv for all voxels + sorted repair rows 1..np-1 for multi-point voxels.
// Rows >= np already zero (init); row 0 written by k_assign.
__global__ void k_write(const void* pts, const int* dflag, const int* cnt,
                        const int* lists, const int* total, float* out) {
    int v = blockIdx.x * blockDim.x + threadIdx.x;
    if (v >= MAXV) return;
    int T = *total;
    if (T > MAXV) T = MAXV;
    if (v >= T) { out[OUT_NPV + v] = 0.0f; return; }
    int c = cnt[v];
    int np = 1 + c;
    if (np > MAXP) np = MAXP;
    out[OUT_NPV + v] = (float)np;
    if (c <= 0) return;
    int m = (c < LCAP) ? c : LCAP;
    int idx[LCAP];
    for (int j = 0; j < m; j++) idx[j] = lists[v * LCAP + j];
    for (int a = 1; a < m; a++) {  // sort duplicate indices ascending
        int kk = idx[a];
        int b = a - 1;
        while (b >= 0 && idx[b] > kk) { idx[b + 1] = idx[b]; b--; }
        idx[b + 1] = kk;
    }
    int bf = *dflag;
    float* dst = out + (size_t)v * MAXP * 5;
    for (int r = 1; r < np; r++) {
        int p = idx[r - 1];
        for (int j = 0; j < 5; j++)
            dst[r * 5 + j] = bfround(load_ch(pts, p, j, bf));
    }
}

extern "C" void kernel_launch(void* const* d_in, const int* in_sizes, int n_in,
                              void* d_out, int out_size, void* d_ws, size_t ws_size,
                              hipStream_t stream) {
    (void)n_in; (void)out_size;
    const void* pts = d_in[0];
    int N = in_sizes[0] / 5;
    float* out = (float*)d_out;
    if (N <= 0 || N > 16384 * 256) return;

    int nb = (N + 255) / 256;

    // ws: tab[hcap]*8 | pflags[N pad256] | bsums/bpre[16384] | total dflag ocount
    //     | cnt[MAXV] | lists[MAXV*LCAP] | extras[nb*SEGC]*8 | bcount[nb] | ovf
    size_t npad = ((size_t)N + 255) & ~(size_t)255;
    size_t fixed = npad + 16384 * 8 + 512 + (size_t)MAXV * 4
                 + (size_t)MAXV * LCAP * 4 + (size_t)nb * SEGC * 8
                 + (size_t)nb * 4 + (size_t)OCAP * 8;
    int hcap = 0;
    if (ws_size >= fixed + (((size_t)8) << 22))      hcap = 1 << 22;  // ~52 MB
    else if (ws_size >= fixed + (((size_t)8) << 21)) hcap = 1 << 21;  // ~35 MB
    if (hcap == 0) return;
    unsigned hmask = (unsigned)(hcap - 1);

    char* w = (char*)d_ws;
    u64* tab    = (u64*)w;  w += (size_t)hcap * 8;
    u8*  pflags = (u8*)w;   w += npad;
    int* bsums  = (int*)w;  w += 16384 * 4;
    int* bpre   = (int*)w;  w += 16384 * 4;
    int* total  = (int*)w;  w += 128;
    int* dflag  = (int*)w;  w += 128;
    u32* ocount = (u32*)w;  w += 256;
    int* cnt    = (int*)w;  w += (size_t)MAXV * 4;
    int* lists  = (int*)w;  w += (size_t)MAXV * LCAP * 4;
    u64* extras = (u64*)w;  w += (size_t)nb * SEGC * 8;
    u32* bcount = (u32*)w;  w += (size_t)nb * 4;
    u64* ovf    = (u64*)w;

    int nbh = (hcap + 255) / 256;

    k_init<<<4096, 256, 0, stream>>>(out, tab, cnt, hcap, N,
                                     (const u16*)pts, dflag, ocount, total);
    Voxelization_87136296501765_kernel<<<nb, 256, 0, stream>>>(
        pts, N, dflag, tab, hmask, extras, bcount, ovf, ocount, pflags);
    k_clear<<<nb + OCAP / 256, 256, 0, stream>>>(extras, bcount, ovf, ocount,
                                                 nb, pflags);
    k_scan1<<<nb, 256, 0, stream>>>(pflags, bsums, N);
    k_scan2<<<1, 256, 0, stream>>>(bsums, bpre, nb, total, out);
    k_assign<<<nbh, 256, 0, stream>>>(tab, hcap, pflags, bpre, pts, dflag, out);
    k_extras<<<nb + OCAP / 256, 256, 0, stream>>>(extras, bcount, ovf, ocount,
                                                  nb, tab, cnt, lists);
    k_write<<<(MAXV + 255) / 256, 256, 0, stream>>>(pts, dflag, cnt, lists,
                                                    total, out);
}


// Round 15
// 258.943 us; speedup vs baseline: 1.7840x; 1.0788x over previous
//

#include <hip/hip_runtime.h>
#include <hip/hip_bf16.h>

// Deterministic hard_voxelize. Round 15: the hash table is write-only after
// insert (except ~49K extras lookups). k_assign iterates POINTS (coalesced;
// rank v monotone in i so firsts[] writes are near-coalesced; key recompute
// only for the ~154K points with v<MAXV). k_write is the sole output writer
// (coors coalesced in v, full 10x5 block per voxel, npv) -> k_init no longer
// touches d_out; k_assign no longer reads/rewrites the 33.5MB table.
// Measured laws: insert = 1 random 64B-line RMW/point ~= 122us (floor);
// single-hot-line device atomics ~7ns each (R12); per-pass byte-shaving of
// L2-resident data ~nil (R14 post-mortem).

#define MAXV 150000
#define MAXP 10
#define LCAP 12
#define GXC 1504
#define GYC 1504
#define GZC 40
#define SEGC 32            // extras segment per 256-pt block (expect ~6)
#define OCAP (1 << 16)     // global overflow (adversarial only)

#define OUT_COORS 7500000
#define OUT_NPV   7950000
#define OUT_VNUM  8100000

typedef unsigned char u8;
typedef unsigned short u16;
typedef unsigned int u32;
typedef unsigned long long u64;
#define EMPTY64 0xFFFFFFFFFFFFFFFFULL

__device__ __forceinline__ u16 f2bf(float v) {  // round-to-nearest-even
    u32 b = __float_as_uint(v);
    return (u16)((b + 0x7FFFu + ((b >> 16) & 1u)) >> 16);
}
__device__ __forceinline__ float bf2f(u16 u) {
    return __uint_as_float(((u32)u) << 16);
}
__device__ __forceinline__ float bfround(float v) { return bf2f(f2bf(v)); }

// Init (+ fused dtype detect in block 0): tab=EMPTY, cnt=0, counters=0.
// Does NOT touch d_out (k_write/k_scan2 cover it completely).
__global__ void k_init(u64* tab, int* cnt, int hcap, int N,
                       const u16* raw, int* dflag, u32* ocount, int* total) {
    if (blockIdx.x == 0) {
        __shared__ int v32;
        __shared__ int v16;
        if (threadIdx.x == 0) { v32 = 0; v16 = 0; }
        __syncthreads();
        int r = (int)threadIdx.x * 37;
        if (r >= N) r = N > 0 ? N - 1 : 0;
        const float* p32 = (const float*)raw;
        float a3 = p32[r * 5 + 3];
        float a4 = p32[r * 5 + 4];
        float b3 = bf2f(raw[r * 5 + 3]);
        float b4 = bf2f(raw[r * 5 + 4]);
        int ok32 = (a3 == a3) && (a4 == a4) &&
                   (a3 >= -0.001f) && (a3 <= 1.001f) && (a4 >= -0.001f) && (a4 <= 1.001f);
        int okbf = (b3 == b3) && (b4 == b4) &&
                   (b3 >= -0.001f) && (b3 <= 1.001f) && (b4 >= -0.001f) && (b4 <= 1.001f);
        if (ok32) atomicAdd(&v32, 1);
        if (okbf) atomicAdd(&v16, 1);
        __syncthreads();
        if (threadIdx.x == 0) *dflag = (v16 > v32) ? 1 : 0;
    }
    int stride = gridDim.x * blockDim.x;
    for (int i = blockIdx.x * blockDim.x + threadIdx.x; i < hcap; i += stride) {
        tab[i] = EMPTY64;
        if (i < MAXV) cnt[i] = 0;
        if (i == 0) { *ocount = 0u; *total = 0; }
    }
}

__device__ __forceinline__ float load_ch(const void* pts, int i, int j, int bf) {
    if (bf) return bf2f(((const u16*)pts)[i * 5 + j]);
    return ((const float*)pts)[i * 5 + j];
}

// Exact f32 sub+div+floor, matching reference arithmetic. -1 if out of range.
__device__ __forceinline__ int point_key(const void* pts, int i, int bf) {
    float x = load_ch(pts, i, 0, bf);
    float y = load_ch(pts, i, 1, bf);
    float z = load_ch(pts, i, 2, bf);
    int cx = (int)floorf((x - (-75.2f)) / 0.1f);
    int cy = (int)floorf((y - (-75.2f)) / 0.1f);
    int cz = (int)floorf((z - (-2.0f)) / 0.15f);
    if (cx < 0 || cx >= GXC || cy < 0 || cy >= GYC || cz < 0 || cz >= GZC) return -1;
    return (cz * GYC + cy) * GXC + cx;
}

// Canonical kernel: packed insert (key<<32|min_idx), duplicate emission into
// per-block segments (LDS counter), coalesced validity flag write.
__global__ void Voxelization_87136296501765_kernel(
        const void* pts, int N, const int* dflag,
        u64* tab, unsigned hmask, u64* extras, u32* bcount,
        u64* ovf, u32* ocount, u8* flags) {
    __shared__ u32 s_cnt;
    if (threadIdx.x == 0) s_cnt = 0;
    __syncthreads();
    int i = blockIdx.x * blockDim.x + threadIdx.x;
    bool has_extra = false;
    u32 eslot = 0, eidx = 0;
    if (i < N) {
        int key = point_key(pts, i, *dflag);
        flags[i] = (u8)(key >= 0);  // firsts keep 1; k_clear zeroes dups
        if (key >= 0) {
            u64 mine = ((u64)(u32)key << 32) | (u32)i;
            unsigned slot = ((unsigned)key * 2654435761u) & hmask;
            for (;;) {
                u64 prev = atomicCAS(&tab[slot], EMPTY64, mine);
                if (prev == EMPTY64) break;           // first writer, no extra
                if ((u32)(prev >> 32) == (u32)key) {  // same voxel -> duplicate
                    u32 pm = (u32)prev;
                    if (pm > (u32)i) {
                        u64 old = atomicMin(&tab[slot], mine);
                        u32 om = (u32)old;
                        eidx = (om > (u32)i) ? om : (u32)i;  // displaced or self
                    } else {
                        eidx = (u32)i;                       // self is extra
                    }
                    eslot = slot;
                    has_extra = true;
                    break;
                }
                slot = (slot + 1) & hmask;
            }
        }
    }
    if (has_extra) {
        u32 pos = atomicAdd(&s_cnt, 1u);  // LDS atomic, block-local
        u64 rec = ((u64)eslot << 32) | eidx;
        if (pos < SEGC) {
            extras[(size_t)blockIdx.x * SEGC + pos] = rec;
        } else {
            u32 op = atomicAdd(ocount, 1u);  // adversarial-only path
            if (op < OCAP) ovf[op] = rec;
        }
    }
    __syncthreads();
    if (threadIdx.x == 0) bcount[blockIdx.x] = s_cnt;
}

// Clear non-first flags (~49K random bytes).
__global__ void k_clear(const u64* extras, const u32* bcount, const u64* ovf,
                        const u32* ocount, int nb, u8* flags) {
    int b = blockIdx.x;
    u64 rec;
    if (b < nb) {
        u32 c = bcount[b];
        if (c > SEGC) c = SEGC;
        if (threadIdx.x >= c) return;
        rec = extras[(size_t)b * SEGC + threadIdx.x];
    } else {
        u32 j = (u32)(b - nb) * 256 + threadIdx.x;
        u32 oc = *ocount;
        if (oc > OCAP) oc = OCAP;
        if (j >= oc) return;
        rec = ovf[j];
    }
    flags[(u32)rec] = 0;
}

// flags -> prefix (separate array; flags preserved for k_assign) + bsums.
__global__ void k_scan1(const u8* flags, u8* prefix, int* bsums, int n) {
    __shared__ int sh[256];
    int t = threadIdx.x;
    int i = blockIdx.x * 256 + t;
    int v = (i < n) ? (int)flags[i] : 0;
    sh[t] = v;
    __syncthreads();
    for (int off = 1; off < 256; off <<= 1) {
        int xv = (t >= off) ? sh[t - off] : 0;
        __syncthreads();
        sh[t] += xv;
        __syncthreads();
    }
    if (i < n) prefix[i] = (u8)(sh[t] - v);
    if (t == 255) bsums[blockIdx.x] = sh[255];
}

// Chunk-serial single-block scan of bsums -> bpre; writes total + vnum.
__global__ void k_scan2(const int* bsums, int* bpre, int nb, int* total, float* out) {
    __shared__ int sh[256];
    int t = threadIdx.x;
    int C = (nb + 255) / 256;
    int lo = t * C;
    int hi = lo + C < nb ? lo + C : nb;
    int s = 0;
    for (int i = lo; i < hi; i++) s += bsums[i];
    sh[t] = s;
    __syncthreads();
    for (int off = 1; off < 256; off <<= 1) {
        int xv = (t >= off) ? sh[t - off] : 0;
        __syncthreads();
        sh[t] += xv;
        __syncthreads();
    }
    int run = sh[t] - s;
    for (int i = lo; i < hi; i++) { bpre[i] = run; run += bsums[i]; }
    if (t == 255) {
        int T = sh[255];
        *total = T;
        if (T > MAXV) T = MAXV;
        out[OUT_VNUM] = bfround((float)T);
    }
}

// Points-domain assign + fused extras binning (tail work per block).
// Blocks [0,nb): point i -> if first: v = prefix+bpre; if v<MAXV (only the
// first ~MAXV ranks, i.e. small i -> coalesced): firsts[v] = (key<<32)|i.
// Then the block's extras segment: slot -> f (tab low word, random 4B) -> v
// -> cnt/lists. Blocks [nb,..): overflow records.
__global__ void k_assign(const void* pts, int N, const int* dflag,
                         const u8* flags, const u8* prefix, const int* bpre,
                         const u64* tab, const u64* extras, const u32* bcount,
                         const u64* ovf, const u32* ocount, int nb,
                         u64* firsts, int* cnt, int* lists) {
    int b = blockIdx.x;
    int t = threadIdx.x;
    int i = b * 256 + t;
    if (b < nb && i < N && flags[i]) {
        int v = (int)prefix[i] + bpre[i >> 8];
        if (v < MAXV) {
            int key = point_key(pts, i, *dflag);  // valid by construction
            firsts[v] = ((u64)(u32)key << 32) | (u32)i;
        }
    }
    // extras phase
    u64 rec;
    if (b < nb) {
        u32 c = bcount[b];
        if (c > SEGC) c = SEGC;
        if (t >= (int)c) return;
        rec = extras[(size_t)b * SEGC + t];
    } else {
        u32 j = (u32)(b - nb) * 256 + t;
        u32 oc = *ocount;
        if (oc > OCAP) oc = OCAP;
        if (j >= oc) return;
        rec = ovf[j];
    }
    u32 slot = (u32)(rec >> 32);
    u32 pidx = (u32)rec;
    u32 f = ((const u32*)tab)[(size_t)slot << 1];  // LE low word = min idx
    int v = (int)prefix[f] + bpre[f >> 8];
    if (v >= MAXV) return;
    int pos = atomicAdd(&cnt[v], 1);
    if (pos < LCAP) lists[v * LCAP + pos] = (int)pidx;
}

// Sole output writer (d_out is poisoned each call): per v writes the full
// 10x5 voxel block, coors (coalesced in v), npv.
__global__ void k_write(const void* pts, const int* dflag, const u64* firsts,
                        const int* cnt, const int* lists, const int* total,
                        float* out) {
    int v = blockIdx.x * blockDim.x + threadIdx.x;
    if (v >= MAXV) return;
    int T = *total;
    if (T > MAXV) T = MAXV;
    float* dst = out + (size_t)v * MAXP * 5;
    if (v >= T) {
        for (int j = 0; j < MAXP * 5; j++) dst[j] = 0.0f;
        out[OUT_COORS + v * 3 + 0] = -1.0f;
        out[OUT_COORS + v * 3 + 1] = -1.0f;
        out[OUT_COORS + v * 3 + 2] = -1.0f;
        out[OUT_NPV + v] = 0.0f;
        return;
    }
    u64 fe = firsts[v];
    u32 key = (u32)(fe >> 32);
    int f = (int)(u32)fe;
    int cx = (int)(key % GXC);
    u32 r = key / GXC;
    int cy = (int)(r % GYC);
    int cz = (int)(r / GYC);
    out[OUT_COORS + v * 3 + 0] = bfround((float)cz);
    out[OUT_COORS + v * 3 + 1] = bfround((float)cy);
    out[OUT_COORS + v * 3 + 2] = bfround((float)cx);
    int c = cnt[v];
    int np = 1 + c;
    if (np > MAXP) np = MAXP;
    out[OUT_NPV + v] = (float)np;
    int bf = *dflag;
    for (int j = 0; j < 5; j++) dst[j] = bfround(load_ch(pts, f, j, bf));
    if (c > 0) {
        int m = (c < LCAP) ? c : LCAP;
        int idx[LCAP];
        for (int j = 0; j < m; j++) idx[j] = lists[v * LCAP + j];
        for (int a = 1; a < m; a++) {  // sort dup indices -> insertion order
            int kk = idx[a];
            int b2 = a - 1;
            while (b2 >= 0 && idx[b2] > kk) { idx[b2 + 1] = idx[b2]; b2--; }
            idx[b2 + 1] = kk;
        }
        for (int rr = 1; rr < np; rr++) {
            int p = idx[rr - 1];
            for (int j = 0; j < 5; j++)
                dst[rr * 5 + j] = bfround(load_ch(pts, p, j, bf));
        }
    }
    for (int rr = np; rr < MAXP; rr++)
        for (int j = 0; j < 5; j++) dst[rr * 5 + j] = 0.0f;
}

extern "C" void kernel_launch(void* const* d_in, const int* in_sizes, int n_in,
                              void* d_out, int out_size, void* d_ws, size_t ws_size,
                              hipStream_t stream) {
    (void)n_in; (void)out_size;
    const void* pts = d_in[0];
    int N = in_sizes[0] / 5;
    float* out = (float*)d_out;
    if (N <= 0 || N > 16384 * 256) return;

    int nb = (N + 255) / 256;

    // ws: tab[hcap]*8 | flags[npad] | prefix[npad] | bsums/bpre[16384] |
    //     total dflag ocount | firsts[MAXV]*8 | cnt[MAXV] | lists[MAXV*LCAP]
    //     | extras[nb*SEGC]*8 | bcount[nb] | ovf[OCAP]*8
    size_t npad = ((size_t)N + 255) & ~(size_t)255;
    size_t fixed = 2 * npad + 16384 * 8 + 512 + (size_t)MAXV * 8
                 + (size_t)MAXV * 4 + (size_t)MAXV * LCAP * 4
                 + (size_t)nb * SEGC * 8 + (size_t)nb * 4 + (size_t)OCAP * 8;
    int hcap = 0;
    if (ws_size >= fixed + (((size_t)8) << 22))      hcap = 1 << 22;  // ~49 MB
    else if (ws_size >= fixed + (((size_t)8) << 21)) hcap = 1 << 21;  // ~32 MB
    if (hcap == 0) return;
    unsigned hmask = (unsigned)(hcap - 1);

    char* w = (char*)d_ws;
    u64* tab    = (u64*)w;  w += (size_t)hcap * 8;
    u8*  flags  = (u8*)w;   w += npad;
    u8*  prefix = (u8*)w;   w += npad;
    int* bsums  = (int*)w;  w += 16384 * 4;
    int* bpre   = (int*)w;  w += 16384 * 4;
    int* total  = (int*)w;  w += 128;
    int* dflag  = (int*)w;  w += 128;
    u32* ocount = (u32*)w;  w += 256;
    u64* firsts = (u64*)w;  w += (size_t)MAXV * 8;
    int* cnt    = (int*)w;  w += (size_t)MAXV * 4;
    int* lists  = (int*)w;  w += (size_t)MAXV * LCAP * 4;
    u64* extras = (u64*)w;  w += (size_t)nb * SEGC * 8;
    u32* bcount = (u32*)w;  w += (size_t)nb * 4;
    u64* ovf    = (u64*)w;

    k_init<<<4096, 256, 0, stream>>>(tab, cnt, hcap, N, (const u16*)pts,
                                     dflag, ocount, total);
    Voxelization_87136296501765_kernel<<<nb, 256, 0, stream>>>(
        pts, N, dflag, tab, hmask, extras, bcount, ovf, ocount, flags);
    k_clear<<<nb + OCAP / 256, 256, 0, stream>>>(extras, bcount, ovf, ocount,
                                                 nb, flags);
    k_scan1<<<nb, 256, 0, stream>>>(flags, prefix, bsums, N);
    k_scan2<<<1, 256, 0, stream>>>(bsums, bpre, nb, total, out);
    k_assign<<<nb + OCAP / 256, 256, 0, stream>>>(
        pts, N, dflag, flags, prefix, bpre, tab, extras, bcount, ovf, ocount,
        nb, firsts, cnt, lists);
    k_write<<<(MAXV + 255) / 256, 256, 0, stream>>>(pts, dflag, firsts, cnt,
                                                    lists, total, out);
}
